// Round 1
// baseline (958.884 us; speedup 1.0000x reference)
//
#include <hip/hip_runtime.h>
#include <hip/hip_bf16.h>

#define IN_DIM 300
#define XDIM   320      // x row padded 300 -> 320 (zeros)
#define MEM    1024
#define KP     1408     // padded K for h-GEMMs: 1024 + 320 + 64 zeros; 1408 = 44*32 = 11*128
#define NTREE  16383
#define NLEAF  8192

typedef _Float16 half8 __attribute__((ext_vector_type(8)));
typedef float    f32x4 __attribute__((ext_vector_type(4)));

__device__ __forceinline__ float sigmoidf_(float x) { return 1.0f / (1.0f + expf(-x)); }

#define GLOAD_LDS16(g, l) \
    __builtin_amdgcn_global_load_lds((const __attribute__((address_space(1))) void*)(g), \
                                     (__attribute__((address_space(3))) void*)(l), 16, 0, 0)

// ---------------------------------------------------------------------------
// Pack: embs -> x16 (stride 320, zero-padded); weights -> fp16 B matrices.
// Biou rows: [0,1024)=i gate, [1024,2048)=o, [2048,3072)=u; row layout
// [Wh(1024) | Wx(300) | zeros...] stride KP. Bf likewise for the f gate.
// ---------------------------------------------------------------------------
__global__ void pack_kernel(
    const float* __restrict__ embs,
    const float* __restrict__ Wix, const float* __restrict__ Wih,
    const float* __restrict__ Wfx, const float* __restrict__ Wfh,
    const float* __restrict__ Wox, const float* __restrict__ Woh,
    const float* __restrict__ Wux, const float* __restrict__ Wuh,
    _Float16* __restrict__ x16, _Float16* __restrict__ Biou, _Float16* __restrict__ Bf)
{
    long long idx = (long long)blockIdx.x * blockDim.x + threadIdx.x;
    const long long n_x    = (long long)NTREE * XDIM;
    const long long n_biou = 3072LL * KP;
    const long long n_bf   = 1024LL * KP;
    if (idx < n_x) {
        int node = (int)(idx / XDIM), j = (int)(idx % XDIM);
        x16[idx] = (j < IN_DIM) ? (_Float16)embs[(long long)node * IN_DIM + j] : (_Float16)0.f;
        return;
    }
    idx -= n_x;
    if (idx < n_biou) {
        int m = (int)(idx / KP), k = (int)(idx % KP);
        int g = m >> 10, mm = m & 1023;
        const float* Wh = (g == 0) ? Wih : (g == 1) ? Woh : Wuh;
        const float* Wx = (g == 0) ? Wix : (g == 1) ? Wox : Wux;
        float v = 0.f;
        if (k < MEM) v = Wh[(long long)mm * MEM + k];
        else if (k - MEM < IN_DIM) v = Wx[(long long)mm * IN_DIM + (k - MEM)];
        Biou[idx] = (_Float16)v;
        return;
    }
    idx -= n_biou;
    if (idx < n_bf) {
        int m = (int)(idx / KP), k = (int)(idx % KP);
        float v = 0.f;
        if (k < MEM) v = Wfh[(long long)m * MEM + k];
        else if (k - MEM < IN_DIM) v = Wfx[(long long)m * IN_DIM + (k - MEM)];
        Bf[idx] = (_Float16)v;
    }
}

// ---------------------------------------------------------------------------
// Build A rows for one level: rows [0,n) = [h(2r)+h(2r+1) | x(node)], rows
// [n,3n) = [h(child) | x(parent)]. Stride KP, cols >= 1344 zeroed.
// ---------------------------------------------------------------------------
__global__ void build_A(const _Float16* __restrict__ hprev,   // (2n, 1024)
                        const _Float16* __restrict__ x16,     // full tree, stride XDIM
                        _Float16* __restrict__ Abuf, int n, int gx0)
{
    int idx = blockIdx.x * blockDim.x + threadIdx.x;
    int total = 3 * n * (KP / 8);
    if (idx >= total) return;
    int row = idx / (KP / 8), cc = idx % (KP / 8);
    int k = cc * 8;
    half8 v = {};
    if (row < n) {
        if (k < MEM) {
            half8 a = *(const half8*)&hprev[(long long)(2 * row) * MEM + k];
            half8 b = *(const half8*)&hprev[(long long)(2 * row + 1) * MEM + k];
            v = a + b;
        } else if (k < MEM + XDIM) {
            v = *(const half8*)&x16[(long long)(gx0 + row) * XDIM + (k - MEM)];
        }
    } else {
        int r2 = row - n;
        if (k < MEM) {
            v = *(const half8*)&hprev[(long long)r2 * MEM + k];
        } else if (k < MEM + XDIM) {
            v = *(const half8*)&x16[(long long)(gx0 + (r2 >> 1)) * XDIM + (k - MEM)];
        }
    }
    *(half8*)&Abuf[(long long)row * KP + k] = v;
}

// ---------------------------------------------------------------------------
// GEMM: C(MxN) = A(MxK) * B(NxK)^T, fp16 in, fp32 MFMA accum, fp16 out.
// m97 structure: 256 threads = 4 waves (2x2), wave tile (BM/2 x BN/2),
// global_load_lds width 16, single LDS buffer, 2 barriers per K-step.
// ---------------------------------------------------------------------------
template<int BM, int BN, int BK>
__global__ __launch_bounds__(256) void gemm_f16(
    const _Float16* __restrict__ A, int lda,
    const _Float16* __restrict__ B, int ldb,
    _Float16* __restrict__ C, int ldc, int K)
{
    constexpr int FM = BM / 32, FN = BN / 32;
    constexpr int ACH = BM * BK / 8 / 256;   // A 16B-chunks per thread
    constexpr int BCH = BN * BK / 8 / 256;
    constexpr int CPR = BK / 8;              // chunks per row
    __shared__ __align__(16) _Float16 ldsA[BM * BK];
    __shared__ __align__(16) _Float16 ldsB[BN * BK];

    int tid = threadIdx.x;
    int wave = tid >> 6, lane = tid & 63;
    int wr = (wave >> 1) * (BM / 2), wc = (wave & 1) * (BN / 2);
    long long m0 = (long long)blockIdx.x * BM, n0 = (long long)blockIdx.y * BN;
    const _Float16* Ab = A + m0 * lda;
    const _Float16* Bb = B + n0 * ldb;
    f32x4 acc[FM][FN] = {};
    int kq = (lane >> 4) * 8, rs = lane & 15;

    for (int k0 = 0; k0 < K; k0 += BK) {
#pragma unroll
        for (int j = 0; j < ACH; ++j) {
            int chunk = j * 256 + tid;
            int row = chunk / CPR, cir = chunk % CPR;
            int cbase = j * 256 + wave * 64;     // wave-uniform LDS base chunk
            GLOAD_LDS16(Ab + (long long)row * lda + k0 + cir * 8, &ldsA[cbase * 8]);
        }
#pragma unroll
        for (int j = 0; j < BCH; ++j) {
            int chunk = j * 256 + tid;
            int row = chunk / CPR, cir = chunk % CPR;
            int cbase = j * 256 + wave * 64;
            GLOAD_LDS16(Bb + (long long)row * ldb + k0 + cir * 8, &ldsB[cbase * 8]);
        }
        __syncthreads();
#pragma unroll
        for (int kk = 0; kk < BK; kk += 32) {
            half8 a[FM], b[FN];
#pragma unroll
            for (int i = 0; i < FM; ++i) a[i] = *(const half8*)&ldsA[(wr + i * 16 + rs) * BK + kk + kq];
#pragma unroll
            for (int i = 0; i < FN; ++i) b[i] = *(const half8*)&ldsB[(wc + i * 16 + rs) * BK + kk + kq];
#pragma unroll
            for (int mi = 0; mi < FM; ++mi)
#pragma unroll
                for (int ni = 0; ni < FN; ++ni)
                    acc[mi][ni] = __builtin_amdgcn_mfma_f32_16x16x32_f16(a[mi], b[ni], acc[mi][ni], 0, 0, 0);
        }
        __syncthreads();
    }
    // C/D layout: col = lane&15, row = (lane>>4)*4 + reg  [m89-verified]
    long long crb = m0 + wr + (lane >> 4) * 4;
    long long ccb = n0 + wc + rs;
#pragma unroll
    for (int mi = 0; mi < FM; ++mi)
#pragma unroll
        for (int i = 0; i < 4; ++i) {
            long long r = crb + mi * 16 + i;
#pragma unroll
            for (int ni = 0; ni < FN; ++ni)
                C[r * ldc + ccb + ni * 16] = (_Float16)acc[mi][ni][i];
        }
}

// ---------------------------------------------------------------------------
// Combine kernels
// ---------------------------------------------------------------------------
__global__ void combine_leaf(
    const _Float16* __restrict__ houpre,  // (8192, 3072) pre-act i|o|u
    const float* __restrict__ bix, const float* __restrict__ bih,
    const float* __restrict__ box_, const float* __restrict__ boh,
    const float* __restrict__ bux, const float* __restrict__ buh,
    float* __restrict__ cout, _Float16* __restrict__ hout)
{
    int idx = blockIdx.x * blockDim.x + threadIdx.x;   // exactly 8192*1024
    int r = idx >> 10, m = idx & 1023;
    float pi = (float)houpre[(long long)r * 3072 + m]        + bix[m] + bih[m];
    float po = (float)houpre[(long long)r * 3072 + 1024 + m] + box_[m] + boh[m];
    float pu = (float)houpre[(long long)r * 3072 + 2048 + m] + bux[m] + buh[m];
    float i = sigmoidf_(pi), o = sigmoidf_(po), u = tanhf(pu);
    float c = i * u;
    float h = o * tanhf(c);
    cout[idx] = c;
    hout[idx] = (_Float16)h;
}

__global__ void combine_int(
    const _Float16* __restrict__ houpre,  // (>=n, 3072)
    const _Float16* __restrict__ fhpre,   // (>=2n, 1024)
    const float* __restrict__ cprev,      // (2n, 1024)
    const float* __restrict__ bix, const float* __restrict__ bih,
    const float* __restrict__ bfx, const float* __restrict__ bfh,
    const float* __restrict__ box_, const float* __restrict__ boh,
    const float* __restrict__ bux, const float* __restrict__ buh,
    float* __restrict__ cout, _Float16* __restrict__ hout,
    int n, float* __restrict__ finalout)
{
    int idx = blockIdx.x * blockDim.x + threadIdx.x;
    if (idx >= n * 1024) return;
    int r = idx >> 10, m = idx & 1023;
    float pi  = (float)houpre[(long long)r * 3072 + m]        + bix[m] + bih[m];
    float po  = (float)houpre[(long long)r * 3072 + 1024 + m] + box_[m] + boh[m];
    float pu  = (float)houpre[(long long)r * 3072 + 2048 + m] + bux[m] + buh[m];
    float pf0 = (float)fhpre[(long long)(2 * r) * MEM + m]     + bfx[m] + bfh[m];
    float pf1 = (float)fhpre[(long long)(2 * r + 1) * MEM + m] + bfx[m] + bfh[m];
    float i = sigmoidf_(pi), o = sigmoidf_(po), u = tanhf(pu);
    float f0 = sigmoidf_(pf0), f1 = sigmoidf_(pf1);
    float c = i * u + f0 * cprev[(long long)(2 * r) * MEM + m]
                    + f1 * cprev[(long long)(2 * r + 1) * MEM + m];
    float h = o * tanhf(c);
    cout[idx] = c;
    hout[idx] = (_Float16)h;
    if (finalout && r == 0) { finalout[m] = c; finalout[MEM + m] = h; }
}

// ---------------------------------------------------------------------------
extern "C" void kernel_launch(void* const* d_in, const int* in_sizes, int n_in,
                              void* d_out, int out_size, void* d_ws, size_t ws_size,
                              hipStream_t stream)
{
    const float* embs = (const float*)d_in[0];
    const float* Wix = (const float*)d_in[1];  const float* bix = (const float*)d_in[2];
    const float* Wih = (const float*)d_in[3];  const float* bih = (const float*)d_in[4];
    const float* Wfx = (const float*)d_in[5];  const float* bfx = (const float*)d_in[6];
    const float* Wfh = (const float*)d_in[7];  const float* bfh = (const float*)d_in[8];
    const float* Wox = (const float*)d_in[9];  const float* box_ = (const float*)d_in[10];
    const float* Woh = (const float*)d_in[11]; const float* boh = (const float*)d_in[12];
    const float* Wux = (const float*)d_in[13]; const float* bux = (const float*)d_in[14];
    const float* Wuh = (const float*)d_in[15]; const float* buh = (const float*)d_in[16];

    char* p = (char*)d_ws;
    auto carve = [&](size_t bytes) -> char* {
        char* r = p; p += (bytes + 255) & ~(size_t)255; return r;
    };
    _Float16* x16    = (_Float16*)carve((size_t)NTREE * XDIM * 2);   // 10.5 MB
    _Float16* Biou   = (_Float16*)carve((size_t)3072 * KP * 2);      //  8.7 MB
    _Float16* Bf     = (_Float16*)carve((size_t)1024 * KP * 2);      //  2.9 MB
    _Float16* Abuf   = (_Float16*)carve((size_t)12288 * KP * 2);     // 34.6 MB
    _Float16* houpre = (_Float16*)carve((size_t)8192 * 3072 * 2);    // 50.3 MB
    _Float16* fhpre  = (_Float16*)carve((size_t)8192 * 1024 * 2);    // 16.8 MB
    _Float16* Hbuf[2];
    Hbuf[0] = (_Float16*)carve((size_t)8192 * 1024 * 2);
    Hbuf[1] = (_Float16*)carve((size_t)8192 * 1024 * 2);
    float* Cbuf[2];
    Cbuf[0] = (float*)carve((size_t)8192 * 1024 * 4);
    Cbuf[1] = (float*)carve((size_t)8192 * 1024 * 4);
    // total ~225 MB of d_ws

    {
        long long tot = (long long)NTREE * XDIM + 3072LL * KP + 1024LL * KP;
        int blocks = (int)((tot + 255) / 256);
        pack_kernel<<<dim3(blocks), dim3(256), 0, stream>>>(
            embs, Wix, Wih, Wfx, Wfh, Wox, Woh, Wux, Wuh, x16, Biou, Bf);
    }

    // ---- leaf level: lvl=13, n=8192, nodes 8191..16382; only i/o/u needed.
    // B = x-columns of Biou (pointer offset MEM, same ldb), K = XDIM.
    gemm_f16<128, 128, 32><<<dim3(64, 24), dim3(256), 0, stream>>>(
        x16 + (size_t)(NLEAF - 1) * XDIM, XDIM, Biou + MEM, KP, houpre, 3072, XDIM);
    combine_leaf<<<dim3(8192 * 1024 / 256), dim3(256), 0, stream>>>(
        houpre, bix, bih, box_, boh, bux, buh, Cbuf[1], Hbuf[1]);

    int par = 1;
    for (int lvl = 12; lvl >= 0; --lvl) {
        int n = 1 << lvl, gx0 = n - 1;
        int totalA = 3 * n * (KP / 8);
        build_A<<<dim3((totalA + 255) / 256), dim3(256), 0, stream>>>(
            Hbuf[par], x16, Abuf, n, gx0);

        // i/o/u GEMM: M = n, N = 3072
        if (n >= 128)
            gemm_f16<128, 128, 32><<<dim3(n / 128, 24), dim3(256), 0, stream>>>(
                Abuf, KP, Biou, KP, houpre, 3072, KP);
        else
            gemm_f16<64, 128, 128><<<dim3(1, 24), dim3(256), 0, stream>>>(
                Abuf, KP, Biou, KP, houpre, 3072, KP);

        // f GEMM: M = 2n, N = 1024
        int M2 = 2 * n;
        if (M2 >= 128)
            gemm_f16<128, 128, 32><<<dim3(M2 / 128, 8), dim3(256), 0, stream>>>(
                Abuf + (size_t)n * KP, KP, Bf, KP, fhpre, 1024, KP);
        else
            gemm_f16<64, 128, 128><<<dim3(1, 8), dim3(256), 0, stream>>>(
                Abuf + (size_t)n * KP, KP, Bf, KP, fhpre, 1024, KP);

        combine_int<<<dim3((n * 1024 + 255) / 256), dim3(256), 0, stream>>>(
            houpre, fhpre, Cbuf[par], bix, bih, bfx, bfh, box_, boh, bux, buh,
            Cbuf[par ^ 1], Hbuf[par ^ 1], n, (lvl == 0) ? (float*)d_out : nullptr);
        par ^= 1;
    }
}

// Round 2
// 461.211 us; speedup vs baseline: 2.0791x; 2.0791x over previous
//
#include <hip/hip_runtime.h>
#include <hip/hip_bf16.h>

#define IN_DIM 300
#define XDIM   320      // x row padded: 300 vals + bias-one at col 300 + zeros
#define MEM    1024
#define NTREE  16383

typedef _Float16 half8 __attribute__((ext_vector_type(8)));
typedef float    f32x4 __attribute__((ext_vector_type(4)));

__device__ __forceinline__ float sigf(float x) { return 1.0f / (1.0f + __expf(-x)); }
__device__ __forceinline__ float tanhfast(float x) { return 2.0f / (1.0f + __expf(-2.0f * x)) - 1.0f; }

#define GLOAD_LDS16(g, l) \
    __builtin_amdgcn_global_load_lds((const __attribute__((address_space(1))) void*)(g), \
                                     (__attribute__((address_space(3))) void*)(l), 16, 0, 0)

// ---------------------------------------------------------------------------
// Pack (one-time): Wiou16 = [Wih;Woh;Wuh] (3072x1024 fp16), Wfh16 (1024x1024),
// x16 (16384x320: [x | 1.0 | 0...]), Bx (4096x320: [Wgx | bgx+bgh | 0...],
// rows g=i,o,u,f).
// ---------------------------------------------------------------------------
__global__ void pack_kernel(
    const float* __restrict__ embs,
    const float* __restrict__ Wix, const float* __restrict__ bix,
    const float* __restrict__ Wih, const float* __restrict__ bih,
    const float* __restrict__ Wfx, const float* __restrict__ bfx,
    const float* __restrict__ Wfh, const float* __restrict__ bfh,
    const float* __restrict__ Wox, const float* __restrict__ box_,
    const float* __restrict__ Woh, const float* __restrict__ boh,
    const float* __restrict__ Wux, const float* __restrict__ bux,
    const float* __restrict__ Wuh, const float* __restrict__ buh,
    _Float16* __restrict__ Wiou16, _Float16* __restrict__ Wfh16,
    _Float16* __restrict__ x16, _Float16* __restrict__ Bx)
{
    long long idx = (long long)blockIdx.x * blockDim.x + threadIdx.x;
    const long long n_wiou = 3072LL * 1024;
    const long long n_wfh  = 1024LL * 1024;
    const long long n_x    = 16384LL * XDIM;
    const long long n_bx   = 4096LL * XDIM;
    if (idx < n_wiou) {
        int m = (int)(idx >> 10), k = (int)(idx & 1023);
        int g = m >> 10, mm = m & 1023;
        const float* W = (g == 0) ? Wih : (g == 1) ? Woh : Wuh;
        Wiou16[idx] = (_Float16)W[(long long)mm * MEM + k];
        return;
    }
    idx -= n_wiou;
    if (idx < n_wfh) {
        Wfh16[idx] = (_Float16)Wfh[idx];
        return;
    }
    idx -= n_wfh;
    if (idx < n_x) {
        int node = (int)(idx / XDIM), j = (int)(idx % XDIM);
        float v = 0.f;
        if (node < NTREE) {
            if (j < IN_DIM) v = embs[(long long)node * IN_DIM + j];
            else if (j == IN_DIM) v = 1.0f;
        }
        x16[idx] = (_Float16)v;
        return;
    }
    idx -= n_x;
    if (idx < n_bx) {
        int r = (int)(idx / XDIM), j = (int)(idx % XDIM);
        int g = r >> 10, mm = r & 1023;
        const float* Wx = (g == 0) ? Wix : (g == 1) ? Wox : (g == 2) ? Wux : Wfx;
        const float* b1 = (g == 0) ? bix : (g == 1) ? box_ : (g == 2) ? bux : bfx;
        const float* b2 = (g == 0) ? bih : (g == 1) ? boh : (g == 2) ? buh : bfh;
        float v = 0.f;
        if (j < IN_DIM) v = Wx[(long long)mm * IN_DIM + j];
        else if (j == IN_DIM) v = b1[mm] + b2[mm];
        Bx[idx] = (_Float16)v;
    }
}

// ---------------------------------------------------------------------------
// GEMM tile core: C(BMxBN) = A(BMxK) * B(BNxK)^T. fp16 in / f32 MFMA / fp16
// out. 4 waves (2x2), gload_lds width 16 with inverse-swizzled SOURCE +
// XOR-swizzled ds_read (rule 21): kills the row-stride bank conflicts.
// ---------------------------------------------------------------------------
template<int BM, int BN, int BK>
__device__ __forceinline__ void gemm_tile(
    const _Float16* __restrict__ A, int lda,
    const _Float16* __restrict__ B, int ldb,
    _Float16* __restrict__ C, int ldc, int K,
    _Float16* ldsA, _Float16* ldsB)
{
    constexpr int FM = BM / 32, FN = BN / 32;
    constexpr int CPR = BK / 8;          // 16B chunks per row
    constexpr int SWM = CPR - 1;         // swizzle mask
    constexpr int ACH = BM * BK / 2048;  // staging iters (256 thr x 16B)
    constexpr int BCH = BN * BK / 2048;

    int tid = threadIdx.x, wave = tid >> 6, lane = tid & 63;
    int wr = (wave >> 1) * (BM / 2), wc = (wave & 1) * (BN / 2);
    int kq = (lane >> 4) * 8, rs = lane & 15;
    f32x4 acc[FM][FN] = {};

    for (int k0 = 0; k0 < K; k0 += BK) {
#pragma unroll
        for (int j = 0; j < ACH; ++j) {
            int c = j * 256 + tid;
            int row = c / CPR;
            int s = (c ^ row) & SWM;     // inverse-swizzled source slot
            GLOAD_LDS16(A + (long long)row * lda + k0 + s * 8,
                        &ldsA[(j * 256 + wave * 64) * 8]);
        }
#pragma unroll
        for (int j = 0; j < BCH; ++j) {
            int c = j * 256 + tid;
            int row = c / CPR;
            int s = (c ^ row) & SWM;
            GLOAD_LDS16(B + (long long)row * ldb + k0 + s * 8,
                        &ldsB[(j * 256 + wave * 64) * 8]);
        }
        __syncthreads();
#pragma unroll
        for (int kk = 0; kk < BK; kk += 32) {
            half8 a[FM], b[FN];
#pragma unroll
            for (int i = 0; i < FM; ++i) {
                int r = wr + i * 16 + rs;
                int s = ((kk + kq) >> 3) ^ (r & SWM);
                a[i] = *(const half8*)&ldsA[r * BK + s * 8];
            }
#pragma unroll
            for (int i = 0; i < FN; ++i) {
                int r = wc + i * 16 + rs;
                int s = ((kk + kq) >> 3) ^ (r & SWM);
                b[i] = *(const half8*)&ldsB[r * BK + s * 8];
            }
#pragma unroll
            for (int mi = 0; mi < FM; ++mi)
#pragma unroll
                for (int ni = 0; ni < FN; ++ni)
                    acc[mi][ni] = __builtin_amdgcn_mfma_f32_16x16x32_f16(a[mi], b[ni], acc[mi][ni], 0, 0, 0);
        }
        __syncthreads();
    }
    // C/D layout: col = lane&15, row = (lane>>4)*4 + reg  [m89-verified]
    int crb = wr + (lane >> 4) * 4, ccb = wc + rs;
#pragma unroll
    for (int mi = 0; mi < FM; ++mi)
#pragma unroll
        for (int i = 0; i < 4; ++i) {
            long long r = crb + mi * 16 + i;
#pragma unroll
            for (int ni = 0; ni < FN; ++ni)
                C[r * ldc + ccb + ni * 16] = (_Float16)acc[mi][ni][i];
        }
}

template<int BM, int BN, int BK>
__global__ __launch_bounds__(256) void gemm_f16(
    const _Float16* __restrict__ A, int lda,
    const _Float16* __restrict__ B, int ldb,
    _Float16* __restrict__ C, int ldc, int K)
{
    __shared__ __align__(16) _Float16 ldsA[BM * BK];
    __shared__ __align__(16) _Float16 ldsB[BN * BK];
    gemm_tile<BM, BN, BK>(A + (long long)blockIdx.x * BM * lda, lda,
                          B + (long long)blockIdx.y * BN * ldb, ldb,
                          C + (long long)blockIdx.x * BM * ldc + (long long)blockIdx.y * BN,
                          ldc, K, ldsA, ldsB);
}

// Fused per-level GEMM: part1 = hsum @ Wiou^T (n x 3072), part2 = H @ Wfh^T
// (2n x 1024). Both K=1024. Block split by blockIdx.x.
template<int BM1, int BM2, int BK>
__global__ __launch_bounds__(256) void gemm_level(
    const _Float16* __restrict__ Hsum, const _Float16* __restrict__ Hc,
    const _Float16* __restrict__ Wiou, const _Float16* __restrict__ Wf,
    _Float16* __restrict__ houpre, _Float16* __restrict__ fpre,
    int G1, int G2)
{
    constexpr int BMX = (BM1 > BM2) ? BM1 : BM2;
    __shared__ __align__(16) _Float16 ldsA[BMX * BK];
    __shared__ __align__(16) _Float16 ldsB[128 * BK];
    int bx = blockIdx.x;
    if (bx < G1 * 24) {
        int nb = bx / G1, mb = bx % G1;
        gemm_tile<BM1, 128, BK>(Hsum + (long long)mb * BM1 * 1024, 1024,
                                Wiou + (long long)nb * 128 * 1024, 1024,
                                houpre + (long long)mb * BM1 * 3072 + nb * 128, 3072,
                                1024, ldsA, ldsB);
    } else {
        int b2 = bx - G1 * 24;
        int nb = b2 / G2, mb = b2 % G2;
        gemm_tile<BM2, 128, BK>(Hc + (long long)mb * BM2 * 1024, 1024,
                                Wf + (long long)nb * 128 * 1024, 1024,
                                fpre + (long long)mb * BM2 * 1024 + nb * 128, 1024,
                                1024, ldsA, ldsB);
    }
}

// ---------------------------------------------------------------------------
// Leaf combine: nodes 8191..16382. Pre-acts = Xpre rows (biases folded).
// c = i*u; h = o*tanh(c). Emits cleaf (fp16), H rows, and hsum pairs.
// ---------------------------------------------------------------------------
__global__ void leaf_combine(const _Float16* __restrict__ XpI,
                             _Float16* __restrict__ cleaf,
                             _Float16* __restrict__ hout,
                             _Float16* __restrict__ hsum)
{
    int idx = blockIdx.x * blockDim.x + threadIdx.x;   // 4096*128 exact
    int r = idx >> 7, m8 = (idx & 127) * 8;
    float hs[8];
#pragma unroll
    for (int j = 0; j < 8; ++j) hs[j] = 0.f;
#pragma unroll
    for (int t = 0; t < 2; ++t) {
        long long l = 2 * r + t;
        long long node = 8191 + l;
        half8 vi = *(const half8*)&XpI[node * 3072 + m8];
        half8 vo = *(const half8*)&XpI[node * 3072 + 1024 + m8];
        half8 vu = *(const half8*)&XpI[node * 3072 + 2048 + m8];
        half8 cv, hv;
#pragma unroll
        for (int j = 0; j < 8; ++j) {
            float i = sigf((float)vi[j]);
            float o = sigf((float)vo[j]);
            float u = tanhfast((float)vu[j]);
            float c = i * u;
            float h = o * tanhfast(c);
            cv[j] = (_Float16)c; hv[j] = (_Float16)h; hs[j] += h;
        }
        *(half8*)&cleaf[l * 1024 + m8] = cv;
        *(half8*)&hout[l * 1024 + m8] = hv;
    }
    half8 sv;
#pragma unroll
    for (int j = 0; j < 8; ++j) sv[j] = (_Float16)hs[j];
    *(half8*)&hsum[(long long)r * 1024 + m8] = sv;
}

// ---------------------------------------------------------------------------
// Internal-level combine: gates from houpre + Xpre, f per child from fpre +
// Xpre_f(parent), c = i*u + f0*c0 + f1*c1, h = o*tanh(c). Emits c, H, hsum.
// At lvl0 (n==1) writes d_out = [c; h] f32 instead.
// ---------------------------------------------------------------------------
template<bool C16>
__global__ void combine_level(
    const _Float16* __restrict__ houpre, const _Float16* __restrict__ fpre,
    const void* __restrict__ cprevp,
    const _Float16* __restrict__ XpI, const _Float16* __restrict__ XpF,
    float* __restrict__ cout, _Float16* __restrict__ hout, _Float16* __restrict__ hsum,
    int n, int gx0, float* __restrict__ fin)
{
    int idx = blockIdx.x * blockDim.x + threadIdx.x;
    int npairs = (n > 1) ? (n >> 1) : 1;
    if (idx >= npairs * 128) return;
    int r = idx >> 7, m8 = (idx & 127) * 8;
    float hs[8];
#pragma unroll
    for (int j = 0; j < 8; ++j) hs[j] = 0.f;
    int pmax = (n > 1) ? 2 : 1;
    for (int t = 0; t < pmax; ++t) {
        int p = 2 * r + t;
        long long node = gx0 + p;
        half8 phi = *(const half8*)&houpre[(long long)p * 3072 + m8];
        half8 pho = *(const half8*)&houpre[(long long)p * 3072 + 1024 + m8];
        half8 phu = *(const half8*)&houpre[(long long)p * 3072 + 2048 + m8];
        half8 pxi = *(const half8*)&XpI[node * 3072 + m8];
        half8 pxo = *(const half8*)&XpI[node * 3072 + 1024 + m8];
        half8 pxu = *(const half8*)&XpI[node * 3072 + 2048 + m8];
        half8 pf0 = *(const half8*)&fpre[(long long)(2 * p) * 1024 + m8];
        half8 pf1 = *(const half8*)&fpre[(long long)(2 * p + 1) * 1024 + m8];
        half8 pxf = *(const half8*)&XpF[node * 1024 + m8];
        float c0[8], c1[8];
        if (C16) {
            const _Float16* cp = (const _Float16*)cprevp;
            half8 a = *(const half8*)&cp[(long long)(2 * p) * 1024 + m8];
            half8 b = *(const half8*)&cp[(long long)(2 * p + 1) * 1024 + m8];
#pragma unroll
            for (int j = 0; j < 8; ++j) { c0[j] = (float)a[j]; c1[j] = (float)b[j]; }
        } else {
            const float* cp = (const float*)cprevp;
            f32x4 a0 = *(const f32x4*)&cp[(long long)(2 * p) * 1024 + m8];
            f32x4 a1 = *(const f32x4*)&cp[(long long)(2 * p) * 1024 + m8 + 4];
            f32x4 b0 = *(const f32x4*)&cp[(long long)(2 * p + 1) * 1024 + m8];
            f32x4 b1 = *(const f32x4*)&cp[(long long)(2 * p + 1) * 1024 + m8 + 4];
#pragma unroll
            for (int j = 0; j < 4; ++j) { c0[j] = a0[j]; c0[j + 4] = a1[j]; c1[j] = b0[j]; c1[j + 4] = b1[j]; }
        }
        float cw[8], hw[8];
#pragma unroll
        for (int j = 0; j < 8; ++j) {
            float i  = sigf((float)phi[j] + (float)pxi[j]);
            float o  = sigf((float)pho[j] + (float)pxo[j]);
            float u  = tanhfast((float)phu[j] + (float)pxu[j]);
            float f0 = sigf((float)pf0[j] + (float)pxf[j]);
            float f1 = sigf((float)pf1[j] + (float)pxf[j]);
            float c = i * u + f0 * c0[j] + f1 * c1[j];
            float h = o * tanhfast(c);
            cw[j] = c; hw[j] = h; hs[j] += h;
        }
        if (fin) {                      // lvl0: write [c;h] f32 to d_out
            f32x4 v0 = {cw[0], cw[1], cw[2], cw[3]}, v1 = {cw[4], cw[5], cw[6], cw[7]};
            f32x4 w0 = {hw[0], hw[1], hw[2], hw[3]}, w1 = {hw[4], hw[5], hw[6], hw[7]};
            *(f32x4*)&fin[m8] = v0;            *(f32x4*)&fin[m8 + 4] = v1;
            *(f32x4*)&fin[1024 + m8] = w0;     *(f32x4*)&fin[1024 + m8 + 4] = w1;
        } else {
            f32x4 v0 = {cw[0], cw[1], cw[2], cw[3]}, v1 = {cw[4], cw[5], cw[6], cw[7]};
            *(f32x4*)&cout[(long long)p * 1024 + m8] = v0;
            *(f32x4*)&cout[(long long)p * 1024 + m8 + 4] = v1;
            half8 hv;
#pragma unroll
            for (int j = 0; j < 8; ++j) hv[j] = (_Float16)hw[j];
            *(half8*)&hout[(long long)p * 1024 + m8] = hv;
        }
    }
    if (!fin) {
        half8 sv;
#pragma unroll
        for (int j = 0; j < 8; ++j) sv[j] = (_Float16)hs[j];
        *(half8*)&hsum[(long long)r * 1024 + m8] = sv;
    }
}

// ---------------------------------------------------------------------------
extern "C" void kernel_launch(void* const* d_in, const int* in_sizes, int n_in,
                              void* d_out, int out_size, void* d_ws, size_t ws_size,
                              hipStream_t stream)
{
    const float* embs = (const float*)d_in[0];
    const float* Wix = (const float*)d_in[1];  const float* bix = (const float*)d_in[2];
    const float* Wih = (const float*)d_in[3];  const float* bih = (const float*)d_in[4];
    const float* Wfx = (const float*)d_in[5];  const float* bfx = (const float*)d_in[6];
    const float* Wfh = (const float*)d_in[7];  const float* bfh = (const float*)d_in[8];
    const float* Wox = (const float*)d_in[9];  const float* box_ = (const float*)d_in[10];
    const float* Woh = (const float*)d_in[11]; const float* boh = (const float*)d_in[12];
    const float* Wux = (const float*)d_in[13]; const float* bux = (const float*)d_in[14];
    const float* Wuh = (const float*)d_in[15]; const float* buh = (const float*)d_in[16];

    char* p = (char*)d_ws;
    auto carve = [&](size_t bytes) -> char* {
        char* r = p; p += (bytes + 255) & ~(size_t)255; return r;
    };
    _Float16* Wiou16 = (_Float16*)carve((size_t)3072 * 1024 * 2);   //   6.3 MB
    _Float16* Wfh16  = (_Float16*)carve((size_t)1024 * 1024 * 2);   //   2.1 MB
    _Float16* XpI    = (_Float16*)carve((size_t)16384 * 3072 * 2);  // 100.7 MB
    _Float16* XpF    = (_Float16*)carve((size_t)8192 * 1024 * 2);   //  16.8 MB
    _Float16* fpre   = (_Float16*)carve((size_t)8192 * 1024 * 2);   //  16.8 MB
    _Float16* H_A    = (_Float16*)carve((size_t)8192 * 1024 * 2);   //  16.8 MB
    _Float16* H_B    = (_Float16*)carve((size_t)4096 * 1024 * 2);   //   8.4 MB
    _Float16* Hsum   = (_Float16*)carve((size_t)4096 * 1024 * 2);   //   8.4 MB
    _Float16* Cleaf  = (_Float16*)carve((size_t)8192 * 1024 * 2);   //  16.8 MB
    float*    Cping  = (float*)carve((size_t)4096 * 1024 * 4);      //  16.8 MB
    float*    Cpong  = (float*)carve((size_t)2048 * 1024 * 4);      //   8.4 MB
    // total ~218 MB (<= round-1's proven 225 MB usage)
    // Aliases (stream-ordered, write-after-last-read):
    _Float16* houpre = XpI + (size_t)8192 * 3072;   // lives in XpI's leaf half
    _Float16* x16    = fpre;                        // dead after Xpre GEMMs
    _Float16* Bx     = fpre + (size_t)16384 * XDIM;

    {   // pack
        long long tot = 3072LL * 1024 + 1024LL * 1024 + 16384LL * XDIM + 4096LL * XDIM;
        pack_kernel<<<dim3((int)((tot + 255) / 256)), dim3(256), 0, stream>>>(
            embs, Wix, bix, Wih, bih, Wfx, bfx, Wfh, bfh,
            Wox, box_, Woh, boh, Wux, bux, Wuh, buh,
            Wiou16, Wfh16, x16, Bx);
    }

    // Xpre GEMMs (biases folded): XpI = x @ [Wix;Wox;Wux]^T  (16384 x 3072, K=320)
    gemm_f16<128, 128, 32><<<dim3(128, 24), dim3(256), 0, stream>>>(
        x16, XDIM, Bx, XDIM, XpI, 3072, XDIM);
    // XpF = x(internal) @ Wfx^T  (8192 x 1024, K=320)
    gemm_f16<128, 128, 32><<<dim3(64, 8), dim3(256), 0, stream>>>(
        x16, XDIM, Bx + (size_t)3072 * XDIM, XDIM, XpF, 1024, XDIM);

    // Leaf level (no GEMM needed)
    leaf_combine<<<dim3(2048), dim3(256), 0, stream>>>(XpI, Cleaf, H_A, Hsum);

    const void* cprev = Cleaf;
    float* cbufs[2] = {Cping, Cpong};
    int ci = 0;
    _Float16* hcur = H_A;
    _Float16* hnext = H_B;

    for (int lvl = 12; lvl >= 0; --lvl) {
        int n = 1 << lvl;
        int G1, G2;
        if (n >= 1024) {
            G1 = n / 128; G2 = 2 * n / 128;
            gemm_level<128, 128, 32><<<dim3(G1 * 24 + G2 * 8), dim3(256), 0, stream>>>(
                Hsum, hcur, Wiou16, Wfh16, houpre, fpre, G1, G2);
        } else if (n >= 128) {
            G1 = n / 128; G2 = 2 * n / 128;
            gemm_level<128, 128, 128><<<dim3(G1 * 24 + G2 * 8), dim3(256), 0, stream>>>(
                Hsum, hcur, Wiou16, Wfh16, houpre, fpre, G1, G2);
        } else if (n == 64) {
            G1 = 1; G2 = 1;
            gemm_level<64, 128, 128><<<dim3(G1 * 24 + G2 * 8), dim3(256), 0, stream>>>(
                Hsum, hcur, Wiou16, Wfh16, houpre, fpre, G1, G2);
        } else {
            G1 = 1; G2 = 1;
            gemm_level<64, 64, 128><<<dim3(G1 * 24 + G2 * 8), dim3(256), 0, stream>>>(
                Hsum, hcur, Wiou16, Wfh16, houpre, fpre, G1, G2);
        }

        int npairs = (n > 1) ? (n >> 1) : 1;
        int blocks = (npairs * 128 + 255) / 256;
        float* fin = (lvl == 0) ? (float*)d_out : nullptr;
        if (lvl == 12)
            combine_level<true><<<dim3(blocks), dim3(256), 0, stream>>>(
                houpre, fpre, cprev, XpI, XpF, cbufs[ci], hnext, Hsum, n, n - 1, fin);
        else
            combine_level<false><<<dim3(blocks), dim3(256), 0, stream>>>(
                houpre, fpre, cprev, XpI, XpF, cbufs[ci], hnext, Hsum, n, n - 1, fin);

        cprev = cbufs[ci];
        ci ^= 1;
        _Float16* tmp = hcur; hcur = hnext; hnext = tmp;
    }
}